// Round 5
// baseline (436.565 us; speedup 1.0000x reference)
//
#include <hip/hip_runtime.h>

#define N_NODES 50000
#define N_EDGES 800000
#define NF 128
#define BN_EPS 1e-5f
#define G_ROWS 32
#define GBLOCKS ((N_NODES + G_ROWS - 1) / G_ROWS)   // 1563
#define NB 1568   // padded partials pitch
#define AP 136  // bf16 A-tile pitch (shorts)
#define HP 132  // fp32 H-tile pitch
#define CAP 32        // bucket capacity per node (Poisson(16) degrees, max ~36)
#define OVFCAP 8192   // overflow-edge capacity (expected ~12 used)
#define NSLICE 8
#define SLICE_N (N_NODES / NSLICE)   // 6250
#define SC_BLK 1024   // scatter blocks (multiple of 8)
#define CV_BLK 512    // conversion blocks
#define NCHUNK ((N_EDGES + 255) / 256)  // 3125

typedef __attribute__((ext_vector_type(8))) short short8;
typedef __attribute__((ext_vector_type(4))) float f32x4;

__device__ __forceinline__ unsigned short f2bf(float f) {
    union { float f; unsigned int i; } v; v.f = f;
    unsigned int r = (v.i + 0x7fffu + ((v.i >> 16) & 1u)) >> 16;
    return (unsigned short)r;
}
__device__ __forceinline__ float bf2f(unsigned short u) {
    union { unsigned int i; float f; } v; v.i = ((unsigned int)u) << 16; return v.f;
}
__device__ __forceinline__ float bflo(unsigned int u) { return bf2f((unsigned short)(u & 0xffffu)); }
__device__ __forceinline__ float bfhi(unsigned int u) { return bf2f((unsigned short)(u >> 16)); }

#define SETUP_C (N_NODES * NF / 4)
#define SETUP_P (128 * 128)

// ---- One-pass bucket-CSR build, XCD-partitioned, + bf16 conversions.
// Round-4 PMC: unpartitioned scatter wrote 60.8 MB (64B line per 4B random write --
// line ping-pong between non-coherent per-XCD L2s). Fix: blocks in group s =
// blockIdx&7 (round-robin XCD mapping, perf-only assumption) stream ALL edges but
// scatter only dst in slice s -> each counts/bucket line owned by ONE XCD.
// Blocks >= SC_BLK do the streaming conversions (x->bf16, W1/W2->bf16).
__global__ __launch_bounds__(256) void scatter_build(
    const int* __restrict__ ei,
    int* __restrict__ counts, int* __restrict__ ovfcnt,
    int* __restrict__ ovf, int* __restrict__ bucket,
    const float* __restrict__ x, unsigned short* __restrict__ xb,
    const float* __restrict__ W1, const float* __restrict__ W2,
    unsigned short* __restrict__ Wb1, unsigned short* __restrict__ Wb2,
    int do_convert) {
    int b = blockIdx.x;
    int t = threadIdx.x;
    if (b < SC_BLK) {
        int sl = b & 7;
        int g = b >> 3;                     // 0..SC_BLK/8-1
        int lo = sl * SLICE_N;
        int hi = lo + SLICE_N;
        for (int chunk = g; chunk < NCHUNK; chunk += SC_BLK / 8) {
            int e = chunk * 256 + t;
            if (e < N_EDGES) {
                int dst = ei[N_EDGES + e];   // coalesced stream
                int src = ei[e];             // coalesced stream
                if (dst >= lo && dst < hi) {
                    int k = atomicAdd(&counts[dst], 1);
                    if (k < CAP) {
                        bucket[dst * CAP + k] = src;
                    } else {
                        int o = atomicAdd(ovfcnt, 1);
                        if (o < OVFCAP) { ovf[2 * o] = dst; ovf[2 * o + 1] = src; }
                    }
                }
            }
        }
    } else {
        int i0 = (b - SC_BLK) * 256 + t;
        int stride = CV_BLK * 256;
        if (do_convert) {
            for (int i = i0; i < SETUP_C; i += stride) {
                float4 v = ((const float4*)x)[i];
                ushort4 u;
                u.x = f2bf(v.x); u.y = f2bf(v.y); u.z = f2bf(v.z); u.w = f2bf(v.w);
                ((ushort4*)xb)[i] = u;
            }
        }
        for (int i = i0; i < SETUP_P; i += stride) {
            Wb1[i] = f2bf(W1[i]);
            Wb2[i] = f2bf(W2[i]);
        }
    }
}

// ---- Fused gather + GEMM1 (bf16) + last-block BN fold.
// One block = 32 nodes, 4 waves x 8 nodes; bucket reads wave-uniform -> scalar loads.
// After writing BN partials P, each block fences + tickets; the LAST block re-fences
// (L2 invalidate) and reduces P -> ab, killing the separate bn_reduce dispatch.
__global__ __launch_bounds__(256, 6) void fused_gather_gemm1_bf16(
    const unsigned short* __restrict__ xb,
    const int* __restrict__ counts,
    const int* __restrict__ bucket,
    const int* __restrict__ ovfcnt,
    const int* __restrict__ ovf,
    const unsigned short* __restrict__ Wb,
    const float* __restrict__ b1,
    const float* __restrict__ gamma,
    const float* __restrict__ beta,
    unsigned short* __restrict__ buf,
    float* __restrict__ P,
    float* __restrict__ ab,
    int* __restrict__ done) {
    __shared__ __align__(16) char smem[G_ROWS * HP * 4];   // 16.9 KB, At/Ht aliased
    unsigned short (*At)[AP] = (unsigned short (*)[AP])smem;
    float (*Ht)[HP] = (float (*)[HP])smem;
    float* sred = (float*)smem;                            // reused by BN epilogue
    __shared__ int slast;

    int t = threadIdx.x;
    int wave = t >> 6, lane = t & 63;
    int base = blockIdx.x * G_ROWS;
    int nrows = N_NODES - base; if (nrows > G_ROWS) nrows = G_ROWS;

    const unsigned int* x2 = (const unsigned int*)xb;
    int novf = *ovfcnt; if (novf > OVFCAP) novf = OVFCAP;

    // ---- gather phase: wave handles rows wave*8 .. wave*8+7 ----
    for (int nn = 0; nn < 8; nn++) {
        int r = wave * 8 + nn;
        int node = base + r;
        unsigned int packed = 0u;
        if (node < N_NODES) {
            unsigned int u = x2[(size_t)node * 64 + lane];
            float ax = bflo(u), ay = bfhi(u);
            int deg = counts[node];
            int cnt = deg < CAP ? deg : CAP;
            const int* bkt = bucket + (size_t)node * CAP;
            int e = 0;
            for (; e + 15 < cnt; e += 16) {
                unsigned int uu[16];
#pragma unroll
                for (int k = 0; k < 16; k++) uu[k] = x2[(size_t)bkt[e + k] * 64 + lane];
#pragma unroll
                for (int k = 0; k < 16; k++) { ax += bflo(uu[k]); ay += bfhi(uu[k]); }
            }
            for (; e + 3 < cnt; e += 4) {
                unsigned int u0 = x2[(size_t)bkt[e] * 64 + lane];
                unsigned int u1 = x2[(size_t)bkt[e + 1] * 64 + lane];
                unsigned int u2 = x2[(size_t)bkt[e + 2] * 64 + lane];
                unsigned int u3 = x2[(size_t)bkt[e + 3] * 64 + lane];
                ax += bflo(u0) + bflo(u1) + bflo(u2) + bflo(u3);
                ay += bfhi(u0) + bfhi(u1) + bfhi(u2) + bfhi(u3);
            }
            for (; e < cnt; e++) {
                unsigned int u0 = x2[(size_t)bkt[e] * 64 + lane];
                ax += bflo(u0);
                ay += bfhi(u0);
            }
            if (deg > CAP) {   // overflow list (expected ~12 edges total, L1-hot)
                for (int o = 0; o < novf; o++) {
                    if (ovf[2 * o] == node) {
                        unsigned int u0 = x2[(size_t)ovf[2 * o + 1] * 64 + lane];
                        ax += bflo(u0);
                        ay += bfhi(u0);
                    }
                }
            }
            packed = ((unsigned int)f2bf(ay) << 16) | (unsigned int)f2bf(ax);
        }
        ((unsigned int*)&At[r][0])[lane] = packed;
    }
    __syncthreads();

    // ---- MFMA phase ----
    int m0 = (wave & 1) * 16;
    int n0 = (wave >> 1) * 64;
    int l15 = lane & 15, q = lane >> 4;

    f32x4 acc[4];
#pragma unroll
    for (int i = 0; i < 4; i++) acc[i] = (f32x4){0.f, 0.f, 0.f, 0.f};

#pragma unroll
    for (int kc = 0; kc < 4; kc++) {
        short8 a = *((const short8*)&At[m0 + l15][kc * 32 + q * 8]);
#pragma unroll
        for (int tile = 0; tile < 4; tile++) {
            short8 b = *((const short8*)(Wb + (size_t)(n0 + 16 * tile + l15) * 128 + kc * 32 + q * 8));
            acc[tile] = __builtin_amdgcn_mfma_f32_16x16x32_bf16(a, b, acc[tile], 0, 0, 0);
        }
    }
    __syncthreads();   // all At reads done before Ht overwrites the same LDS

#pragma unroll
    for (int tile = 0; tile < 4; tile++) {
        int col = n0 + 16 * tile + l15;
        float bias = b1[col];
#pragma unroll
        for (int reg = 0; reg < 4; reg++) {
            int row = q * 4 + reg;
            Ht[m0 + row][col] = fmaxf(acc[tile][reg] + bias, 0.f);
        }
    }
    __syncthreads();

    // ---- epilogue: bf16 h -> buf, BN partials -> P ----
    for (int i = t; i < G_ROWS * 32; i += 256) {
        int r = i >> 5, c4 = i & 31;
        int row = base + r;
        if (row < N_NODES) {
            float4 v = *((const float4*)&Ht[r][c4 * 4]);
            ushort4 u;
            u.x = f2bf(v.x); u.y = f2bf(v.y); u.z = f2bf(v.z); u.w = f2bf(v.w);
            *((ushort4*)(buf + (size_t)row * NF + c4 * 4)) = u;
        }
    }

    {
        int f = t & 127;
        bool issq = (t >= 128);
        float s = 0.f;
        for (int r = 0; r < nrows; r++) {
            float v = Ht[r][f];
            s += issq ? v * v : v;
        }
        P[(size_t)t * NB + blockIdx.x] = s;
    }

    // ---- last-block BN reduce + fold ----
    __threadfence();          // release: P writes visible device-wide
    __syncthreads();
    if (t == 0) slast = (atomicAdd(done, 1) == (int)gridDim.x - 1);
    __syncthreads();
    if (slast) {
        __threadfence();      // acquire: invalidate stale L2 lines of P
        const float* row = P + (size_t)t * NB;   // row t == P[t][*]
        float4 a0 = make_float4(0.f, 0.f, 0.f, 0.f);
        int k = 0;
        for (; k + 3 < GBLOCKS; k += 4) {
            float4 v = *((const float4*)(row + k));
            a0.x += v.x; a0.y += v.y; a0.z += v.z; a0.w += v.w;
        }
        float s = a0.x + a0.y + a0.z + a0.w;
        for (; k < GBLOCKS; k++) s += row[k];
        __syncthreads();      // Ht reads done (P loop) before sred overwrite
        sred[t] = s;
        __syncthreads();
        if (t < 128) {
            float mean = sred[t] * (1.0f / N_NODES);
            float var = sred[128 + t] * (1.0f / N_NODES) - mean * mean;
            float rstd = rsqrtf(var + BN_EPS);
            float aa = gamma[t] * rstd;
            ab[t] = aa;
            ab[128 + t] = beta[t] - mean * aa;
        }
    }
}

// -------- GEMM2 (bf16 in, fp32 out), At/Ht aliased LDS -----------------------
__global__ __launch_bounds__(256) void gemm2_bf16(
    const unsigned short* __restrict__ buf,
    const unsigned short* __restrict__ Wb,
    const float* __restrict__ b2,
    const float* __restrict__ ab,
    float* __restrict__ out) {
    __shared__ __align__(16) char smem[G_ROWS * HP * 4];
    unsigned short (*At)[AP] = (unsigned short (*)[AP])smem;
    float (*Ht)[HP] = (float (*)[HP])smem;

    int t = threadIdx.x;
    int base = blockIdx.x * G_ROWS;
    int nrows = N_NODES - base; if (nrows > G_ROWS) nrows = G_ROWS;

    for (int i = t; i < G_ROWS * 32; i += 256) {
        int r = i >> 5, c4 = i & 31;
        ushort4 u = make_ushort4(0, 0, 0, 0);
        if (r < nrows) {
            ushort4 hv = *((const ushort4*)(buf + (size_t)(base + r) * NF + c4 * 4));
            float4 av = ((const float4*)ab)[c4];
            float4 cv = ((const float4*)(ab + 128))[c4];
            u.x = f2bf(bf2f(hv.x) * av.x + cv.x);
            u.y = f2bf(bf2f(hv.y) * av.y + cv.y);
            u.z = f2bf(bf2f(hv.z) * av.z + cv.z);
            u.w = f2bf(bf2f(hv.w) * av.w + cv.w);
        }
        *((ushort4*)&At[r][c4 * 4]) = u;
    }
    __syncthreads();

    int wave = t >> 6, lane = t & 63;
    int m0 = (wave & 1) * 16;
    int n0 = (wave >> 1) * 64;
    int l15 = lane & 15, q = lane >> 4;

    f32x4 acc[4];
#pragma unroll
    for (int i = 0; i < 4; i++) acc[i] = (f32x4){0.f, 0.f, 0.f, 0.f};

#pragma unroll
    for (int kc = 0; kc < 4; kc++) {
        short8 a = *((const short8*)&At[m0 + l15][kc * 32 + q * 8]);
#pragma unroll
        for (int tile = 0; tile < 4; tile++) {
            short8 b = *((const short8*)(Wb + (size_t)(n0 + 16 * tile + l15) * 128 + kc * 32 + q * 8));
            acc[tile] = __builtin_amdgcn_mfma_f32_16x16x32_bf16(a, b, acc[tile], 0, 0, 0);
        }
    }
    __syncthreads();   // all At reads done before Ht overwrites the same LDS

#pragma unroll
    for (int tile = 0; tile < 4; tile++) {
        int col = n0 + 16 * tile + l15;
        float bias = b2[col];
#pragma unroll
        for (int reg = 0; reg < 4; reg++) {
            int row = q * 4 + reg;
            Ht[m0 + row][col] = acc[tile][reg] + bias;
        }
    }
    __syncthreads();

    for (int i = t; i < G_ROWS * 32; i += 256) {
        int r = i >> 5, c4 = i & 31;
        int row = base + r;
        if (row < N_NODES)
            *((float4*)(out + (size_t)row * NF + c4 * 4)) = *((const float4*)&Ht[r][c4 * 4]);
    }
}

// =============== fp32 fallback path (ws too small for bf16 tables) ===========
__global__ void finalize_bn(const float* __restrict__ stats,
                            const float* __restrict__ gamma,
                            const float* __restrict__ beta,
                            float* __restrict__ ab) {
    int f = threadIdx.x;
    if (f < 128) {
        float mean = stats[f] * (1.0f / N_NODES);
        float var = stats[128 + f] * (1.0f / N_NODES) - mean * mean;
        float rstd = rsqrtf(var + BN_EPS);
        float a = gamma[f] * rstd;
        float c = beta[f] - mean * a;
        ab[f] = a;
        ab[128 + f] = c;
    }
}

__global__ __launch_bounds__(256) void fused_gather_gemm1_f32(
    const float* __restrict__ xv,
    const int* __restrict__ counts,
    const int* __restrict__ bucket,
    const int* __restrict__ ovfcnt,
    const int* __restrict__ ovf,
    const unsigned short* __restrict__ Wb,
    const float* __restrict__ b1,
    float* __restrict__ hout,
    float* __restrict__ stats) {
    __shared__ unsigned short At[G_ROWS][AP];
    __shared__ float Ht[G_ROWS][HP];

    int t = threadIdx.x;
    int wave = t >> 6, lane = t & 63;
    int base = blockIdx.x * G_ROWS;
    int nrows = N_NODES - base; if (nrows > G_ROWS) nrows = G_ROWS;

    const float2* xf2 = (const float2*)xv;
    int novf = *ovfcnt; if (novf > OVFCAP) novf = OVFCAP;

    for (int nn = 0; nn < 8; nn++) {
        int r = wave * 8 + nn;
        int node = base + r;
        float2 acc = make_float2(0.f, 0.f);
        if (node < N_NODES) {
            acc = xf2[(size_t)node * 64 + lane];
            int deg = counts[node];
            int cnt = deg < CAP ? deg : CAP;
            const int* bkt = bucket + (size_t)node * CAP;
            for (int e = 0; e < cnt; e++) {
                float2 v0 = xf2[(size_t)bkt[e] * 64 + lane];
                acc.x += v0.x;
                acc.y += v0.y;
            }
            if (deg > CAP) {
                for (int o = 0; o < novf; o++) {
                    if (ovf[2 * o] == node) {
                        float2 v0 = xf2[(size_t)ovf[2 * o + 1] * 64 + lane];
                        acc.x += v0.x;
                        acc.y += v0.y;
                    }
                }
            }
        }
        unsigned int packed = ((unsigned int)f2bf(acc.y) << 16) | (unsigned int)f2bf(acc.x);
        *((unsigned int*)&At[r][lane * 2]) = packed;
    }
    __syncthreads();

    int m0 = (wave & 1) * 16;
    int n0 = (wave >> 1) * 64;
    int l15 = lane & 15, q = lane >> 4;

    f32x4 acc[4];
#pragma unroll
    for (int i = 0; i < 4; i++) acc[i] = (f32x4){0.f, 0.f, 0.f, 0.f};

#pragma unroll
    for (int kc = 0; kc < 4; kc++) {
        short8 a = *((const short8*)&At[m0 + l15][kc * 32 + q * 8]);
#pragma unroll
        for (int tile = 0; tile < 4; tile++) {
            short8 b = *((const short8*)(Wb + (size_t)(n0 + 16 * tile + l15) * 128 + kc * 32 + q * 8));
            acc[tile] = __builtin_amdgcn_mfma_f32_16x16x32_bf16(a, b, acc[tile], 0, 0, 0);
        }
    }

#pragma unroll
    for (int tile = 0; tile < 4; tile++) {
        int col = n0 + 16 * tile + l15;
        float bias = b1[col];
#pragma unroll
        for (int reg = 0; reg < 4; reg++) {
            int row = q * 4 + reg;
            Ht[m0 + row][col] = fmaxf(acc[tile][reg] + bias, 0.f);
        }
    }
    __syncthreads();

    for (int i = t; i < G_ROWS * 32; i += 256) {
        int r = i >> 5, c4 = i & 31;
        int row = base + r;
        if (row < N_NODES)
            *((float4*)(hout + (size_t)row * NF + c4 * 4)) = *((const float4*)&Ht[r][c4 * 4]);
    }

    if (t < 128) {
        float s = 0.f, sq = 0.f;
        for (int r = 0; r < nrows; r++) {
            float v = Ht[r][t];
            s += v; sq += v * v;
        }
        atomicAdd(&stats[t], s);
        atomicAdd(&stats[128 + t], sq);
    }
}

__global__ __launch_bounds__(256) void gemm2_f32(
    float* __restrict__ h,
    const unsigned short* __restrict__ Wb,
    const float* __restrict__ b2,
    const float* __restrict__ ab) {
    __shared__ unsigned short At[G_ROWS][AP];
    __shared__ float Ht[G_ROWS][HP];

    int t = threadIdx.x;
    int base = blockIdx.x * G_ROWS;
    int nrows = N_NODES - base; if (nrows > G_ROWS) nrows = G_ROWS;

    for (int i = t; i < G_ROWS * 32; i += 256) {
        int r = i >> 5, c4 = i & 31;
        float4 v = make_float4(0.f, 0.f, 0.f, 0.f);
        if (r < nrows) {
            float4 hv = ((const float4*)(h + (size_t)(base + r) * NF))[c4];
            float4 av = ((const float4*)ab)[c4];
            float4 cv = ((const float4*)(ab + 128))[c4];
            v.x = hv.x * av.x + cv.x;
            v.y = hv.y * av.y + cv.y;
            v.z = hv.z * av.z + cv.z;
            v.w = hv.w * av.w + cv.w;
        }
        ushort4 u;
        u.x = f2bf(v.x); u.y = f2bf(v.y); u.z = f2bf(v.z); u.w = f2bf(v.w);
        *((ushort4*)&At[r][c4 * 4]) = u;
    }
    __syncthreads();

    int wave = t >> 6, lane = t & 63;
    int m0 = (wave & 1) * 16;
    int n0 = (wave >> 1) * 64;
    int l15 = lane & 15, q = lane >> 4;

    f32x4 acc[4];
#pragma unroll
    for (int i = 0; i < 4; i++) acc[i] = (f32x4){0.f, 0.f, 0.f, 0.f};

#pragma unroll
    for (int kc = 0; kc < 4; kc++) {
        short8 a = *((const short8*)&At[m0 + l15][kc * 32 + q * 8]);
#pragma unroll
        for (int tile = 0; tile < 4; tile++) {
            short8 b = *((const short8*)(Wb + (size_t)(n0 + 16 * tile + l15) * 128 + kc * 32 + q * 8));
            acc[tile] = __builtin_amdgcn_mfma_f32_16x16x32_bf16(a, b, acc[tile], 0, 0, 0);
        }
    }

#pragma unroll
    for (int tile = 0; tile < 4; tile++) {
        int col = n0 + 16 * tile + l15;
        float bias = b2[col];
#pragma unroll
        for (int reg = 0; reg < 4; reg++) {
            int row = q * 4 + reg;
            Ht[m0 + row][col] = acc[tile][reg] + bias;
        }
    }
    __syncthreads();

    for (int i = t; i < G_ROWS * 32; i += 256) {
        int r = i >> 5, c4 = i & 31;
        int row = base + r;
        if (row < N_NODES)
            *((float4*)(h + (size_t)row * NF + c4 * 4)) = *((const float4*)&Ht[r][c4 * 4]);
    }
}

extern "C" void kernel_launch(void* const* d_in, const int* in_sizes, int n_in,
                              void* d_out, int out_size, void* d_ws, size_t ws_size,
                              hipStream_t stream) {
    const float* x     = (const float*)d_in[0];
    const int*   ei    = (const int*)d_in[1];
    const float* W1    = (const float*)d_in[2];
    const float* b1    = (const float*)d_in[3];
    const float* gamma = (const float*)d_in[4];
    const float* beta  = (const float*)d_in[5];
    const float* W2    = (const float*)d_in[6];
    const float* b2    = (const float*)d_in[7];

    float* out = (float*)d_out;

    // Workspace layout (~33.9 MB)
    float*          stats    = (float*)d_ws;                    // 256 f
    float*          ab       = stats + 256;                     // 256 f
    float*          P        = ab + 256;                        // 256*NB f (~1.6 MB)
    unsigned short* Wb1      = (unsigned short*)(P + 256 * NB); // 16384 us
    unsigned short* Wb2      = Wb1 + 128 * 128;                 // 16384 us
    int*            counts   = (int*)(Wb2 + 128 * 128);         // 50000 i
    int*            ovfcnt   = counts + N_NODES;                // 16 i (ovfcnt[0]=ovf, [1]=done)
    int*            ovf      = ovfcnt + 16;                     // 2*OVFCAP i (64 KB)
    int*            bucket   = ovf + 2 * OVFCAP;                // 50000*CAP i (6.4 MB)
    unsigned short* xb       = (unsigned short*)(bucket + (size_t)N_NODES * CAP); // 12.8 MB
    unsigned short* buf      = xb + (size_t)N_NODES * NF;       // 12.8 MB

    size_t need = (size_t)((char*)(buf + (size_t)N_NODES * NF) - (char*)d_ws);
    size_t need_fb = (size_t)((char*)xb - (char*)d_ws);
    bool bf16_path = ws_size >= need;

    if (bf16_path) {
        hipMemsetAsync(counts, 0, (N_NODES + 16) * sizeof(int), stream);  // counts+ovfcnt+done
        scatter_build<<<SC_BLK + CV_BLK, 256, 0, stream>>>(
            ei, counts, ovfcnt, ovf, bucket, x, xb, W1, W2, Wb1, Wb2, 1);
        fused_gather_gemm1_bf16<<<GBLOCKS, 256, 0, stream>>>(
            xb, counts, bucket, ovfcnt, ovf, Wb1, b1, gamma, beta, buf, P, ab, ovfcnt + 1);
        gemm2_bf16<<<GBLOCKS, 256, 0, stream>>>(buf, Wb2, b2, ab, out);
    } else if (ws_size >= need_fb) {
        hipMemsetAsync(counts, 0, (N_NODES + 16) * sizeof(int), stream);
        hipMemsetAsync(stats, 0, 256 * sizeof(float), stream);
        scatter_build<<<SC_BLK + CV_BLK, 256, 0, stream>>>(
            ei, counts, ovfcnt, ovf, bucket, x, (unsigned short*)0, W1, W2, Wb1, Wb2, 0);
        fused_gather_gemm1_f32<<<GBLOCKS, 256, 0, stream>>>(
            x, counts, bucket, ovfcnt, ovf, Wb1, b1, out, stats);
        finalize_bn<<<1, 128, 0, stream>>>(stats, gamma, beta, ab);
        gemm2_f32<<<GBLOCKS, 256, 0, stream>>>(out, Wb2, b2, ab);
    }
}

// Round 6
// 201.155 us; speedup vs baseline: 2.1703x; 2.1703x over previous
//
#include <hip/hip_runtime.h>

#define N_NODES 50000
#define N_EDGES 800000
#define NF 128
#define BN_EPS 1e-5f
#define G_ROWS 32
#define GBLOCKS ((N_NODES + G_ROWS - 1) / G_ROWS)   // 1563
#define NB 1568   // padded partials pitch
#define AP 136  // bf16 A-tile pitch (shorts)
#define HP 132  // fp32 H-tile pitch
#define CAP 32        // bucket capacity per node (Poisson(16) degrees, max ~36)
#define OVFCAP 8192   // overflow-edge capacity (expected ~12 used)
#define NSLICE 8
#define SLICE_N (N_NODES / NSLICE)   // 6250
#define SC_BLK 1024   // scatter blocks (multiple of 8)
#define CV_BLK 512    // conversion blocks
#define NCHUNK ((N_EDGES + 255) / 256)  // 3125

typedef __attribute__((ext_vector_type(8))) short short8;
typedef __attribute__((ext_vector_type(4))) float f32x4;

__device__ __forceinline__ unsigned short f2bf(float f) {
    union { float f; unsigned int i; } v; v.f = f;
    unsigned int r = (v.i + 0x7fffu + ((v.i >> 16) & 1u)) >> 16;
    return (unsigned short)r;
}
__device__ __forceinline__ float bf2f(unsigned short u) {
    union { unsigned int i; float f; } v; v.i = ((unsigned int)u) << 16; return v.f;
}
__device__ __forceinline__ float bflo(unsigned int u) { return bf2f((unsigned short)(u & 0xffffu)); }
__device__ __forceinline__ float bfhi(unsigned int u) { return bf2f((unsigned short)(u >> 16)); }

#define SETUP_C (N_NODES * NF / 4)
#define SETUP_P (128 * 128)

// ---- One-pass bucket-CSR build, XCD-partitioned, + bf16 conversions.
// Round-4 PMC: unpartitioned scatter wrote 60.8 MB (64B line per 4B random write --
// line ping-pong between non-coherent per-XCD L2s). Fix: group s = blockIdx&7
// (round-robin XCD mapping, perf-only) streams ALL edges but scatters only dst in
// slice s -> each counts/bucket line owned by ONE XCD. Blocks >= SC_BLK do the
// streaming conversions (x->bf16, W1/W2->bf16).
// NOTE (round-5 lesson): NO device-scope fences anywhere near the gather kernel --
// __threadfence() per block forces per-XCD L2 writeback (non-coherent L2s) and
// collapsed the fused kernel 55->295us. BN stays a separate tiny dispatch.
__global__ __launch_bounds__(256) void scatter_build(
    const int* __restrict__ ei,
    int* __restrict__ counts, int* __restrict__ ovfcnt,
    int* __restrict__ ovf, int* __restrict__ bucket,
    const float* __restrict__ x, unsigned short* __restrict__ xb,
    const float* __restrict__ W1, const float* __restrict__ W2,
    unsigned short* __restrict__ Wb1, unsigned short* __restrict__ Wb2,
    int do_convert) {
    int b = blockIdx.x;
    int t = threadIdx.x;
    if (b < SC_BLK) {
        int sl = b & 7;
        int g = b >> 3;                     // 0..SC_BLK/8-1
        int lo = sl * SLICE_N;
        int hi = lo + SLICE_N;
        for (int chunk = g; chunk < NCHUNK; chunk += SC_BLK / 8) {
            int e = chunk * 256 + t;
            if (e < N_EDGES) {
                int dst = ei[N_EDGES + e];   // coalesced stream
                int src = ei[e];             // coalesced stream
                if (dst >= lo && dst < hi) {
                    int k = atomicAdd(&counts[dst], 1);
                    if (k < CAP) {
                        bucket[dst * CAP + k] = src;
                    } else {
                        int o = atomicAdd(ovfcnt, 1);
                        if (o < OVFCAP) { ovf[2 * o] = dst; ovf[2 * o + 1] = src; }
                    }
                }
            }
        }
    } else {
        int i0 = (b - SC_BLK) * 256 + t;
        int stride = CV_BLK * 256;
        if (do_convert) {
            for (int i = i0; i < SETUP_C; i += stride) {
                float4 v = ((const float4*)x)[i];
                ushort4 u;
                u.x = f2bf(v.x); u.y = f2bf(v.y); u.z = f2bf(v.z); u.w = f2bf(v.w);
                ((ushort4*)xb)[i] = u;
            }
        }
        for (int i = i0; i < SETUP_P; i += stride) {
            Wb1[i] = f2bf(W1[i]);
            Wb2[i] = f2bf(W2[i]);
        }
    }
}

// ---- Fused gather + GEMM1 (bf16): byte-identical to the round-4 55.6us version.
// One block = 32 nodes, 4 waves x 8 nodes; bucket reads wave-uniform -> scalar loads.
__global__ __launch_bounds__(256, 6) void fused_gather_gemm1_bf16(
    const unsigned short* __restrict__ xb,
    const int* __restrict__ counts,
    const int* __restrict__ bucket,
    const int* __restrict__ ovfcnt,
    const int* __restrict__ ovf,
    const unsigned short* __restrict__ Wb,
    const float* __restrict__ b1,
    unsigned short* __restrict__ buf,
    float* __restrict__ P) {
    __shared__ __align__(16) char smem[G_ROWS * HP * 4];   // 16.9 KB, At/Ht aliased
    unsigned short (*At)[AP] = (unsigned short (*)[AP])smem;
    float (*Ht)[HP] = (float (*)[HP])smem;

    int t = threadIdx.x;
    int wave = t >> 6, lane = t & 63;
    int base = blockIdx.x * G_ROWS;
    int nrows = N_NODES - base; if (nrows > G_ROWS) nrows = G_ROWS;

    const unsigned int* x2 = (const unsigned int*)xb;
    int novf = *ovfcnt; if (novf > OVFCAP) novf = OVFCAP;

    // ---- gather phase: wave handles rows wave*8 .. wave*8+7 ----
    for (int nn = 0; nn < 8; nn++) {
        int r = wave * 8 + nn;
        int node = base + r;
        unsigned int packed = 0u;
        if (node < N_NODES) {
            unsigned int u = x2[(size_t)node * 64 + lane];
            float ax = bflo(u), ay = bfhi(u);
            int deg = counts[node];
            int cnt = deg < CAP ? deg : CAP;
            const int* bkt = bucket + (size_t)node * CAP;
            int e = 0;
            for (; e + 15 < cnt; e += 16) {
                unsigned int uu[16];
#pragma unroll
                for (int k = 0; k < 16; k++) uu[k] = x2[(size_t)bkt[e + k] * 64 + lane];
#pragma unroll
                for (int k = 0; k < 16; k++) { ax += bflo(uu[k]); ay += bfhi(uu[k]); }
            }
            for (; e + 3 < cnt; e += 4) {
                unsigned int u0 = x2[(size_t)bkt[e] * 64 + lane];
                unsigned int u1 = x2[(size_t)bkt[e + 1] * 64 + lane];
                unsigned int u2 = x2[(size_t)bkt[e + 2] * 64 + lane];
                unsigned int u3 = x2[(size_t)bkt[e + 3] * 64 + lane];
                ax += bflo(u0) + bflo(u1) + bflo(u2) + bflo(u3);
                ay += bfhi(u0) + bfhi(u1) + bfhi(u2) + bfhi(u3);
            }
            for (; e < cnt; e++) {
                unsigned int u0 = x2[(size_t)bkt[e] * 64 + lane];
                ax += bflo(u0);
                ay += bfhi(u0);
            }
            if (deg > CAP) {   // overflow list (expected ~12 edges total, L1-hot)
                for (int o = 0; o < novf; o++) {
                    if (ovf[2 * o] == node) {
                        unsigned int u0 = x2[(size_t)ovf[2 * o + 1] * 64 + lane];
                        ax += bflo(u0);
                        ay += bfhi(u0);
                    }
                }
            }
            packed = ((unsigned int)f2bf(ay) << 16) | (unsigned int)f2bf(ax);
        }
        ((unsigned int*)&At[r][0])[lane] = packed;
    }
    __syncthreads();

    // ---- MFMA phase ----
    int m0 = (wave & 1) * 16;
    int n0 = (wave >> 1) * 64;
    int l15 = lane & 15, q = lane >> 4;

    f32x4 acc[4];
#pragma unroll
    for (int i = 0; i < 4; i++) acc[i] = (f32x4){0.f, 0.f, 0.f, 0.f};

#pragma unroll
    for (int kc = 0; kc < 4; kc++) {
        short8 a = *((const short8*)&At[m0 + l15][kc * 32 + q * 8]);
#pragma unroll
        for (int tile = 0; tile < 4; tile++) {
            short8 b = *((const short8*)(Wb + (size_t)(n0 + 16 * tile + l15) * 128 + kc * 32 + q * 8));
            acc[tile] = __builtin_amdgcn_mfma_f32_16x16x32_bf16(a, b, acc[tile], 0, 0, 0);
        }
    }
    __syncthreads();   // all At reads done before Ht overwrites the same LDS

#pragma unroll
    for (int tile = 0; tile < 4; tile++) {
        int col = n0 + 16 * tile + l15;
        float bias = b1[col];
#pragma unroll
        for (int reg = 0; reg < 4; reg++) {
            int row = q * 4 + reg;
            Ht[m0 + row][col] = fmaxf(acc[tile][reg] + bias, 0.f);
        }
    }
    __syncthreads();

    // ---- epilogue: bf16 h -> buf, BN partials -> P ----
    for (int i = t; i < G_ROWS * 32; i += 256) {
        int r = i >> 5, c4 = i & 31;
        int row = base + r;
        if (row < N_NODES) {
            float4 v = *((const float4*)&Ht[r][c4 * 4]);
            ushort4 u;
            u.x = f2bf(v.x); u.y = f2bf(v.y); u.z = f2bf(v.z); u.w = f2bf(v.w);
            *((ushort4*)(buf + (size_t)row * NF + c4 * 4)) = u;
        }
    }

    {
        int f = t & 127;
        bool issq = (t >= 128);
        float s = 0.f;
        for (int r = 0; r < nrows; r++) {
            float v = Ht[r][f];
            s += issq ? v * v : v;
        }
        P[(size_t)t * NB + blockIdx.x] = s;
    }
}

// ------- BN reduce + fold (separate dispatch; cheap and fence-free) ----------
__global__ __launch_bounds__(256) void bn_reduce(const float* __restrict__ P,
                                                 const float* __restrict__ gamma,
                                                 const float* __restrict__ beta,
                                                 float* __restrict__ ab) {
    __shared__ float s1[256], s2[256];
    int f = blockIdx.x;
    int j = threadIdx.x;
    float a = 0.f, b = 0.f;
    for (int k = j; k < GBLOCKS; k += 256) {
        a += P[(size_t)f * NB + k];
        b += P[(size_t)(128 + f) * NB + k];
    }
    s1[j] = a; s2[j] = b;
    __syncthreads();
    for (int off = 128; off > 0; off >>= 1) {
        if (j < off) { s1[j] += s1[j + off]; s2[j] += s2[j + off]; }
        __syncthreads();
    }
    if (j == 0) {
        float mean = s1[0] * (1.0f / N_NODES);
        float var = s2[0] * (1.0f / N_NODES) - mean * mean;
        float rstd = rsqrtf(var + BN_EPS);
        float aa = gamma[f] * rstd;
        float cc = beta[f] - mean * aa;
        ab[f] = aa;
        ab[128 + f] = cc;
    }
}

// -------- GEMM2 (bf16 in, fp32 out), At/Ht aliased LDS -----------------------
__global__ __launch_bounds__(256) void gemm2_bf16(
    const unsigned short* __restrict__ buf,
    const unsigned short* __restrict__ Wb,
    const float* __restrict__ b2,
    const float* __restrict__ ab,
    float* __restrict__ out) {
    __shared__ __align__(16) char smem[G_ROWS * HP * 4];
    unsigned short (*At)[AP] = (unsigned short (*)[AP])smem;
    float (*Ht)[HP] = (float (*)[HP])smem;

    int t = threadIdx.x;
    int base = blockIdx.x * G_ROWS;
    int nrows = N_NODES - base; if (nrows > G_ROWS) nrows = G_ROWS;

    for (int i = t; i < G_ROWS * 32; i += 256) {
        int r = i >> 5, c4 = i & 31;
        ushort4 u = make_ushort4(0, 0, 0, 0);
        if (r < nrows) {
            ushort4 hv = *((const ushort4*)(buf + (size_t)(base + r) * NF + c4 * 4));
            float4 av = ((const float4*)ab)[c4];
            float4 cv = ((const float4*)(ab + 128))[c4];
            u.x = f2bf(bf2f(hv.x) * av.x + cv.x);
            u.y = f2bf(bf2f(hv.y) * av.y + cv.y);
            u.z = f2bf(bf2f(hv.z) * av.z + cv.z);
            u.w = f2bf(bf2f(hv.w) * av.w + cv.w);
        }
        *((ushort4*)&At[r][c4 * 4]) = u;
    }
    __syncthreads();

    int wave = t >> 6, lane = t & 63;
    int m0 = (wave & 1) * 16;
    int n0 = (wave >> 1) * 64;
    int l15 = lane & 15, q = lane >> 4;

    f32x4 acc[4];
#pragma unroll
    for (int i = 0; i < 4; i++) acc[i] = (f32x4){0.f, 0.f, 0.f, 0.f};

#pragma unroll
    for (int kc = 0; kc < 4; kc++) {
        short8 a = *((const short8*)&At[m0 + l15][kc * 32 + q * 8]);
#pragma unroll
        for (int tile = 0; tile < 4; tile++) {
            short8 b = *((const short8*)(Wb + (size_t)(n0 + 16 * tile + l15) * 128 + kc * 32 + q * 8));
            acc[tile] = __builtin_amdgcn_mfma_f32_16x16x32_bf16(a, b, acc[tile], 0, 0, 0);
        }
    }
    __syncthreads();   // all At reads done before Ht overwrites the same LDS

#pragma unroll
    for (int tile = 0; tile < 4; tile++) {
        int col = n0 + 16 * tile + l15;
        float bias = b2[col];
#pragma unroll
        for (int reg = 0; reg < 4; reg++) {
            int row = q * 4 + reg;
            Ht[m0 + row][col] = acc[tile][reg] + bias;
        }
    }
    __syncthreads();

    for (int i = t; i < G_ROWS * 32; i += 256) {
        int r = i >> 5, c4 = i & 31;
        int row = base + r;
        if (row < N_NODES)
            *((float4*)(out + (size_t)row * NF + c4 * 4)) = *((const float4*)&Ht[r][c4 * 4]);
    }
}

// =============== fp32 fallback path (ws too small for bf16 tables) ===========
__global__ void finalize_bn(const float* __restrict__ stats,
                            const float* __restrict__ gamma,
                            const float* __restrict__ beta,
                            float* __restrict__ ab) {
    int f = threadIdx.x;
    if (f < 128) {
        float mean = stats[f] * (1.0f / N_NODES);
        float var = stats[128 + f] * (1.0f / N_NODES) - mean * mean;
        float rstd = rsqrtf(var + BN_EPS);
        float a = gamma[f] * rstd;
        float c = beta[f] - mean * a;
        ab[f] = a;
        ab[128 + f] = c;
    }
}

__global__ __launch_bounds__(256) void fused_gather_gemm1_f32(
    const float* __restrict__ xv,
    const int* __restrict__ counts,
    const int* __restrict__ bucket,
    const int* __restrict__ ovfcnt,
    const int* __restrict__ ovf,
    const unsigned short* __restrict__ Wb,
    const float* __restrict__ b1,
    float* __restrict__ hout,
    float* __restrict__ stats) {
    __shared__ unsigned short At[G_ROWS][AP];
    __shared__ float Ht[G_ROWS][HP];

    int t = threadIdx.x;
    int wave = t >> 6, lane = t & 63;
    int base = blockIdx.x * G_ROWS;
    int nrows = N_NODES - base; if (nrows > G_ROWS) nrows = G_ROWS;

    const float2* xf2 = (const float2*)xv;
    int novf = *ovfcnt; if (novf > OVFCAP) novf = OVFCAP;

    for (int nn = 0; nn < 8; nn++) {
        int r = wave * 8 + nn;
        int node = base + r;
        float2 acc = make_float2(0.f, 0.f);
        if (node < N_NODES) {
            acc = xf2[(size_t)node * 64 + lane];
            int deg = counts[node];
            int cnt = deg < CAP ? deg : CAP;
            const int* bkt = bucket + (size_t)node * CAP;
            for (int e = 0; e < cnt; e++) {
                float2 v0 = xf2[(size_t)bkt[e] * 64 + lane];
                acc.x += v0.x;
                acc.y += v0.y;
            }
            if (deg > CAP) {
                for (int o = 0; o < novf; o++) {
                    if (ovf[2 * o] == node) {
                        float2 v0 = xf2[(size_t)ovf[2 * o + 1] * 64 + lane];
                        acc.x += v0.x;
                        acc.y += v0.y;
                    }
                }
            }
        }
        unsigned int packed = ((unsigned int)f2bf(acc.y) << 16) | (unsigned int)f2bf(acc.x);
        *((unsigned int*)&At[r][lane * 2]) = packed;
    }
    __syncthreads();

    int m0 = (wave & 1) * 16;
    int n0 = (wave >> 1) * 64;
    int l15 = lane & 15, q = lane >> 4;

    f32x4 acc[4];
#pragma unroll
    for (int i = 0; i < 4; i++) acc[i] = (f32x4){0.f, 0.f, 0.f, 0.f};

#pragma unroll
    for (int kc = 0; kc < 4; kc++) {
        short8 a = *((const short8*)&At[m0 + l15][kc * 32 + q * 8]);
#pragma unroll
        for (int tile = 0; tile < 4; tile++) {
            short8 b = *((const short8*)(Wb + (size_t)(n0 + 16 * tile + l15) * 128 + kc * 32 + q * 8));
            acc[tile] = __builtin_amdgcn_mfma_f32_16x16x32_bf16(a, b, acc[tile], 0, 0, 0);
        }
    }

#pragma unroll
    for (int tile = 0; tile < 4; tile++) {
        int col = n0 + 16 * tile + l15;
        float bias = b1[col];
#pragma unroll
        for (int reg = 0; reg < 4; reg++) {
            int row = q * 4 + reg;
            Ht[m0 + row][col] = fmaxf(acc[tile][reg] + bias, 0.f);
        }
    }
    __syncthreads();

    for (int i = t; i < G_ROWS * 32; i += 256) {
        int r = i >> 5, c4 = i & 31;
        int row = base + r;
        if (row < N_NODES)
            *((float4*)(hout + (size_t)row * NF + c4 * 4)) = *((const float4*)&Ht[r][c4 * 4]);
    }

    if (t < 128) {
        float s = 0.f, sq = 0.f;
        for (int r = 0; r < nrows; r++) {
            float v = Ht[r][t];
            s += v; sq += v * v;
        }
        atomicAdd(&stats[t], s);
        atomicAdd(&stats[128 + t], sq);
    }
}

__global__ __launch_bounds__(256) void gemm2_f32(
    float* __restrict__ h,
    const unsigned short* __restrict__ Wb,
    const float* __restrict__ b2,
    const float* __restrict__ ab) {
    __shared__ unsigned short At[G_ROWS][AP];
    __shared__ float Ht[G_ROWS][HP];

    int t = threadIdx.x;
    int base = blockIdx.x * G_ROWS;
    int nrows = N_NODES - base; if (nrows > G_ROWS) nrows = G_ROWS;

    for (int i = t; i < G_ROWS * 32; i += 256) {
        int r = i >> 5, c4 = i & 31;
        float4 v = make_float4(0.f, 0.f, 0.f, 0.f);
        if (r < nrows) {
            float4 hv = ((const float4*)(h + (size_t)(base + r) * NF))[c4];
            float4 av = ((const float4*)ab)[c4];
            float4 cv = ((const float4*)(ab + 128))[c4];
            v.x = hv.x * av.x + cv.x;
            v.y = hv.y * av.y + cv.y;
            v.z = hv.z * av.z + cv.z;
            v.w = hv.w * av.w + cv.w;
        }
        ushort4 u;
        u.x = f2bf(v.x); u.y = f2bf(v.y); u.z = f2bf(v.z); u.w = f2bf(v.w);
        *((ushort4*)&At[r][c4 * 4]) = u;
    }
    __syncthreads();

    int wave = t >> 6, lane = t & 63;
    int m0 = (wave & 1) * 16;
    int n0 = (wave >> 1) * 64;
    int l15 = lane & 15, q = lane >> 4;

    f32x4 acc[4];
#pragma unroll
    for (int i = 0; i < 4; i++) acc[i] = (f32x4){0.f, 0.f, 0.f, 0.f};

#pragma unroll
    for (int kc = 0; kc < 4; kc++) {
        short8 a = *((const short8*)&At[m0 + l15][kc * 32 + q * 8]);
#pragma unroll
        for (int tile = 0; tile < 4; tile++) {
            short8 b = *((const short8*)(Wb + (size_t)(n0 + 16 * tile + l15) * 128 + kc * 32 + q * 8));
            acc[tile] = __builtin_amdgcn_mfma_f32_16x16x32_bf16(a, b, acc[tile], 0, 0, 0);
        }
    }

#pragma unroll
    for (int tile = 0; tile < 4; tile++) {
        int col = n0 + 16 * tile + l15;
        float bias = b2[col];
#pragma unroll
        for (int reg = 0; reg < 4; reg++) {
            int row = q * 4 + reg;
            Ht[m0 + row][col] = acc[tile][reg] + bias;
        }
    }
    __syncthreads();

    for (int i = t; i < G_ROWS * 32; i += 256) {
        int r = i >> 5, c4 = i & 31;
        int row = base + r;
        if (row < N_NODES)
            *((float4*)(h + (size_t)row * NF + c4 * 4)) = *((const float4*)&Ht[r][c4 * 4]);
    }
}

extern "C" void kernel_launch(void* const* d_in, const int* in_sizes, int n_in,
                              void* d_out, int out_size, void* d_ws, size_t ws_size,
                              hipStream_t stream) {
    const float* x     = (const float*)d_in[0];
    const int*   ei    = (const int*)d_in[1];
    const float* W1    = (const float*)d_in[2];
    const float* b1    = (const float*)d_in[3];
    const float* gamma = (const float*)d_in[4];
    const float* beta  = (const float*)d_in[5];
    const float* W2    = (const float*)d_in[6];
    const float* b2    = (const float*)d_in[7];

    float* out = (float*)d_out;

    // Workspace layout (~33.9 MB)
    float*          stats    = (float*)d_ws;                    // 256 f
    float*          ab       = stats + 256;                     // 256 f
    float*          P        = ab + 256;                        // 256*NB f (~1.6 MB)
    unsigned short* Wb1      = (unsigned short*)(P + 256 * NB); // 16384 us
    unsigned short* Wb2      = Wb1 + 128 * 128;                 // 16384 us
    int*            counts   = (int*)(Wb2 + 128 * 128);         // 50000 i
    int*            ovfcnt   = counts + N_NODES;                // 16 i
    int*            ovf      = ovfcnt + 16;                     // 2*OVFCAP i (64 KB)
    int*            bucket   = ovf + 2 * OVFCAP;                // 50000*CAP i (6.4 MB)
    unsigned short* xb       = (unsigned short*)(bucket + (size_t)N_NODES * CAP); // 12.8 MB
    unsigned short* buf      = xb + (size_t)N_NODES * NF;       // 12.8 MB

    size_t need = (size_t)((char*)(buf + (size_t)N_NODES * NF) - (char*)d_ws);
    size_t need_fb = (size_t)((char*)xb - (char*)d_ws);
    bool bf16_path = ws_size >= need;

    if (bf16_path) {
        hipMemsetAsync(counts, 0, (N_NODES + 16) * sizeof(int), stream);  // counts + ovfcnt
        scatter_build<<<SC_BLK + CV_BLK, 256, 0, stream>>>(
            ei, counts, ovfcnt, ovf, bucket, x, xb, W1, W2, Wb1, Wb2, 1);
        fused_gather_gemm1_bf16<<<GBLOCKS, 256, 0, stream>>>(
            xb, counts, bucket, ovfcnt, ovf, Wb1, b1, buf, P);
        bn_reduce<<<128, 256, 0, stream>>>(P, gamma, beta, ab);
        gemm2_bf16<<<GBLOCKS, 256, 0, stream>>>(buf, Wb2, b2, ab, out);
    } else if (ws_size >= need_fb) {
        hipMemsetAsync(counts, 0, (N_NODES + 16) * sizeof(int), stream);
        hipMemsetAsync(stats, 0, 256 * sizeof(float), stream);
        scatter_build<<<SC_BLK + CV_BLK, 256, 0, stream>>>(
            ei, counts, ovfcnt, ovf, bucket, x, (unsigned short*)0, W1, W2, Wb1, Wb2, 0);
        fused_gather_gemm1_f32<<<GBLOCKS, 256, 0, stream>>>(
            x, counts, bucket, ovfcnt, ovf, Wb1, b1, out, stats);
        finalize_bn<<<1, 128, 0, stream>>>(stats, gamma, beta, ab);
        gemm2_f32<<<GBLOCKS, 256, 0, stream>>>(out, Wb2, b2, ab);
    }
}

// Round 8
// 198.429 us; speedup vs baseline: 2.2001x; 1.0137x over previous
//
#include <hip/hip_runtime.h>

#define N_NODES 50000
#define N_EDGES 800000
#define NF 128
#define BN_EPS 1e-5f
#define G_ROWS 32
#define GBLOCKS ((N_NODES + G_ROWS - 1) / G_ROWS)   // 1563
#define NB 1568   // padded partials pitch
#define AP 136  // bf16 A-tile pitch (shorts)
#define HP 132  // fp32 H-tile pitch
#define CAP 32        // bucket capacity per node (Poisson(16) degrees, max ~36)
#define OVFCAP 8192   // overflow-edge capacity (expected ~12 used)
#define NSLICE 8
#define SLICE_N (N_NODES / NSLICE)   // 6250
#define SC_BLK 1024   // scatter blocks (multiple of 8)
#define CV_BLK 512    // conversion blocks
#define NCHUNK ((N_EDGES + 255) / 256)  // 3125

typedef __attribute__((ext_vector_type(8))) short short8;
typedef __attribute__((ext_vector_type(4))) float f32x4;

__device__ __forceinline__ unsigned short f2bf(float f) {
    union { float f; unsigned int i; } v; v.f = f;
    unsigned int r = (v.i + 0x7fffu + ((v.i >> 16) & 1u)) >> 16;
    return (unsigned short)r;
}
__device__ __forceinline__ float bf2f(unsigned short u) {
    union { unsigned int i; float f; } v; v.i = ((unsigned int)u) << 16; return v.f;
}
__device__ __forceinline__ float bflo(unsigned int u) { return bf2f((unsigned short)(u & 0xffffu)); }
__device__ __forceinline__ float bfhi(unsigned int u) { return bf2f((unsigned short)(u >> 16)); }

#define SETUP_C (N_NODES * NF / 4)
#define SETUP_P (128 * 128)

// ---- One-pass bucket-CSR build, XCD-partitioned, + bf16 conversions (round-6 proven).
__global__ __launch_bounds__(256) void scatter_build(
    const int* __restrict__ ei,
    int* __restrict__ counts, int* __restrict__ ovfcnt,
    int* __restrict__ ovf, int* __restrict__ bucket,
    const float* __restrict__ x, unsigned short* __restrict__ xb,
    const float* __restrict__ W1, const float* __restrict__ W2,
    unsigned short* __restrict__ Wb1, unsigned short* __restrict__ Wb2,
    int do_convert) {
    int b = blockIdx.x;
    int t = threadIdx.x;
    if (b < SC_BLK) {
        int sl = b & 7;
        int g = b >> 3;
        int lo = sl * SLICE_N;
        int hi = lo + SLICE_N;
        for (int chunk = g; chunk < NCHUNK; chunk += SC_BLK / 8) {
            int e = chunk * 256 + t;
            if (e < N_EDGES) {
                int dst = ei[N_EDGES + e];
                int src = ei[e];
                if (dst >= lo && dst < hi) {
                    int k = atomicAdd(&counts[dst], 1);
                    if (k < CAP) {
                        bucket[dst * CAP + k] = src;
                    } else {
                        int o = atomicAdd(ovfcnt, 1);
                        if (o < OVFCAP) { ovf[2 * o] = dst; ovf[2 * o + 1] = src; }
                    }
                }
            }
        }
    } else {
        int i0 = (b - SC_BLK) * 256 + t;
        int stride = CV_BLK * 256;
        if (do_convert) {
            for (int i = i0; i < SETUP_C; i += stride) {
                float4 v = ((const float4*)x)[i];
                ushort4 u;
                u.x = f2bf(v.x); u.y = f2bf(v.y); u.z = f2bf(v.z); u.w = f2bf(v.w);
                ((ushort4*)xb)[i] = u;
            }
        }
        for (int i = i0; i < SETUP_P; i += stride) {
            Wb1[i] = f2bf(W1[i]);
            Wb2[i] = f2bf(W2[i]);
        }
    }
}

// ---- grid barrier: relaxed spin + release flag. Cheap ONLY because all
// cross-phase global writes are device-scope (bypass L2) -> L2 is clean at
// arrival (round-5 lesson: fencing a DIRTY L2 mid-kernel cost 240us).
// Co-residency of all blocks is GUARANTEED by cooperative launch.
__device__ __forceinline__ void gbar(int* cnt, int* flag, int epoch, int nb) {
    __syncthreads();
    if (threadIdx.x == 0) {
        int v = __hip_atomic_fetch_add(cnt, 1, __ATOMIC_ACQ_REL, __HIP_MEMORY_SCOPE_AGENT);
        if (v == nb - 1) {
            __hip_atomic_store(cnt, 0, __ATOMIC_RELAXED, __HIP_MEMORY_SCOPE_AGENT);
            __hip_atomic_store(flag, epoch, __ATOMIC_RELEASE, __HIP_MEMORY_SCOPE_AGENT);
        } else {
            while (__hip_atomic_load(flag, __ATOMIC_RELAXED, __HIP_MEMORY_SCOPE_AGENT) < epoch)
                __builtin_amdgcn_s_sleep(8);
        }
    }
    __syncthreads();
}

// ---- Mega kernel: gather+GEMM1 -> bar -> BN reduce (blocks 0..127) -> bar -> GEMM2.
// Ht (h tile) stays in LDS across both barriers: kills the 25.6MB buf round-trip
// and 2 dispatch boundaries. P and ab cross XCDs via device-scope atomics only.
__global__ __launch_bounds__(256, 7) void mega_bf16(
    const unsigned short* __restrict__ xb,
    const int* __restrict__ counts,
    const int* __restrict__ bucket,
    const int* __restrict__ ovfcnt,
    const int* __restrict__ ovf,
    const unsigned short* __restrict__ Wb1,
    const float* __restrict__ b1,
    const unsigned short* __restrict__ Wb2,
    const float* __restrict__ b2,
    const float* __restrict__ gamma,
    const float* __restrict__ beta,
    float* __restrict__ P,
    float* __restrict__ ab,
    int* __restrict__ bar,
    float* __restrict__ out) {
    __shared__ __align__(16) char smem[G_ROWS * HP * 4];   // 16.9 KB, At/Ht aliased
    __shared__ __align__(16) float saux[512];              // bn reduce / ab staging
    unsigned short (*At)[AP] = (unsigned short (*)[AP])smem;
    float (*Ht)[HP] = (float (*)[HP])smem;

    int t = threadIdx.x;
    int wave = t >> 6, lane = t & 63;
    int base = blockIdx.x * G_ROWS;
    int nrows = N_NODES - base; if (nrows > G_ROWS) nrows = G_ROWS;

    const unsigned int* x2 = (const unsigned int*)xb;
    int novf = *ovfcnt; if (novf > OVFCAP) novf = OVFCAP;

    // ================= Phase B: gather + GEMM1 =================
    for (int nn = 0; nn < 8; nn++) {
        int r = wave * 8 + nn;
        int node = base + r;
        unsigned int packed = 0u;
        if (node < N_NODES) {
            unsigned int u = x2[(size_t)node * 64 + lane];
            float ax = bflo(u), ay = bfhi(u);
            int deg = counts[node];
            int cnt = deg < CAP ? deg : CAP;
            const int* bkt = bucket + (size_t)node * CAP;
            int e = 0;
            for (; e + 15 < cnt; e += 16) {
                unsigned int uu[16];
#pragma unroll
                for (int k = 0; k < 16; k++) uu[k] = x2[(size_t)bkt[e + k] * 64 + lane];
#pragma unroll
                for (int k = 0; k < 16; k++) { ax += bflo(uu[k]); ay += bfhi(uu[k]); }
            }
            for (; e + 3 < cnt; e += 4) {
                unsigned int u0 = x2[(size_t)bkt[e] * 64 + lane];
                unsigned int u1 = x2[(size_t)bkt[e + 1] * 64 + lane];
                unsigned int u2 = x2[(size_t)bkt[e + 2] * 64 + lane];
                unsigned int u3 = x2[(size_t)bkt[e + 3] * 64 + lane];
                ax += bflo(u0) + bflo(u1) + bflo(u2) + bflo(u3);
                ay += bfhi(u0) + bfhi(u1) + bfhi(u2) + bfhi(u3);
            }
            for (; e < cnt; e++) {
                unsigned int u0 = x2[(size_t)bkt[e] * 64 + lane];
                ax += bflo(u0);
                ay += bfhi(u0);
            }
            if (deg > CAP) {
                for (int o = 0; o < novf; o++) {
                    if (ovf[2 * o] == node) {
                        unsigned int u0 = x2[(size_t)ovf[2 * o + 1] * 64 + lane];
                        ax += bflo(u0);
                        ay += bfhi(u0);
                    }
                }
            }
            packed = ((unsigned int)f2bf(ay) << 16) | (unsigned int)f2bf(ax);
        }
        ((unsigned int*)&At[r][0])[lane] = packed;
    }
    __syncthreads();

    {
        int m0 = (wave & 1) * 16;
        int n0 = (wave >> 1) * 64;
        int l15 = lane & 15, q = lane >> 4;
        f32x4 acc[4];
#pragma unroll
        for (int i = 0; i < 4; i++) acc[i] = (f32x4){0.f, 0.f, 0.f, 0.f};
#pragma unroll
        for (int kc = 0; kc < 4; kc++) {
            short8 a = *((const short8*)&At[m0 + l15][kc * 32 + q * 8]);
#pragma unroll
            for (int tile = 0; tile < 4; tile++) {
                short8 b = *((const short8*)(Wb1 + (size_t)(n0 + 16 * tile + l15) * 128 + kc * 32 + q * 8));
                acc[tile] = __builtin_amdgcn_mfma_f32_16x16x32_bf16(a, b, acc[tile], 0, 0, 0);
            }
        }
        __syncthreads();   // At reads done before Ht overwrite
#pragma unroll
        for (int tile = 0; tile < 4; tile++) {
            int col = n0 + 16 * tile + l15;
            float bias = b1[col];
#pragma unroll
            for (int reg = 0; reg < 4; reg++) {
                int row = q * 4 + reg;
                Ht[m0 + row][col] = fmaxf(acc[tile][reg] + bias, 0.f);
            }
        }
    }
    __syncthreads();

    // BN partials -> P via device-scope stores (bypass L2: keeps L2 clean for gbar)
    {
        int f = t & 127;
        bool issq = (t >= 128);
        float s = 0.f;
        for (int r = 0; r < nrows; r++) {
            float v = Ht[r][f];
            s += issq ? v * v : v;
        }
        __hip_atomic_store(&P[(size_t)t * NB + blockIdx.x], s,
                           __ATOMIC_RELAXED, __HIP_MEMORY_SCOPE_AGENT);
    }

    gbar(bar, bar + 1, 1, (int)gridDim.x);

    // ================= Phase C: BN reduce (blocks 0..127) =================
    if (blockIdx.x < 128) {
        int f = blockIdx.x;
        float a = 0.f, b = 0.f;
        for (int k = t; k < GBLOCKS; k += 256) {
            a += __hip_atomic_load(&P[(size_t)f * NB + k], __ATOMIC_RELAXED, __HIP_MEMORY_SCOPE_AGENT);
            b += __hip_atomic_load(&P[(size_t)(128 + f) * NB + k], __ATOMIC_RELAXED, __HIP_MEMORY_SCOPE_AGENT);
        }
        saux[t] = a; saux[256 + t] = b;
        __syncthreads();
        for (int off = 128; off > 0; off >>= 1) {
            if (t < off) { saux[t] += saux[t + off]; saux[256 + t] += saux[256 + t + off]; }
            __syncthreads();
        }
        if (t == 0) {
            float mean = saux[0] * (1.0f / N_NODES);
            float var = saux[256] * (1.0f / N_NODES) - mean * mean;
            float rstd = rsqrtf(var + BN_EPS);
            float aa = gamma[f] * rstd;
            float cc = beta[f] - mean * aa;
            __hip_atomic_store(&ab[f], aa, __ATOMIC_RELAXED, __HIP_MEMORY_SCOPE_AGENT);
            __hip_atomic_store(&ab[128 + f], cc, __ATOMIC_RELAXED, __HIP_MEMORY_SCOPE_AGENT);
        }
    }

    gbar(bar, bar + 1, 2, (int)gridDim.x);

    // ================= Phase D: GEMM2 from LDS-resident Ht =================
    saux[t] = __hip_atomic_load(&ab[t], __ATOMIC_RELAXED, __HIP_MEMORY_SCOPE_AGENT);
    __syncthreads();

    // in-place Ht*a+c -> bf16 At (read-all, sync, write-all: full aliasing)
    {
        float4 hv[4];
#pragma unroll
        for (int it = 0; it < 4; it++) {
            int i = t + it * 256; int r = i >> 5, c4 = i & 31;
            hv[it] = *((const float4*)&Ht[r][c4 * 4]);
        }
        __syncthreads();
#pragma unroll
        for (int it = 0; it < 4; it++) {
            int i = t + it * 256; int r = i >> 5, c4 = i & 31;
            float4 av = *((const float4*)&saux[c4 * 4]);
            float4 cv = *((const float4*)&saux[128 + c4 * 4]);
            ushort4 u;
            u.x = f2bf(hv[it].x * av.x + cv.x);
            u.y = f2bf(hv[it].y * av.y + cv.y);
            u.z = f2bf(hv[it].z * av.z + cv.z);
            u.w = f2bf(hv[it].w * av.w + cv.w);
            *((ushort4*)&At[r][c4 * 4]) = u;
        }
    }
    __syncthreads();

    {
        int m0 = (wave & 1) * 16;
        int n0 = (wave >> 1) * 64;
        int l15 = lane & 15, q = lane >> 4;
        f32x4 acc[4];
#pragma unroll
        for (int i = 0; i < 4; i++) acc[i] = (f32x4){0.f, 0.f, 0.f, 0.f};
#pragma unroll
        for (int kc = 0; kc < 4; kc++) {
            short8 a = *((const short8*)&At[m0 + l15][kc * 32 + q * 8]);
#pragma unroll
            for (int tile = 0; tile < 4; tile++) {
                short8 b = *((const short8*)(Wb2 + (size_t)(n0 + 16 * tile + l15) * 128 + kc * 32 + q * 8));
                acc[tile] = __builtin_amdgcn_mfma_f32_16x16x32_bf16(a, b, acc[tile], 0, 0, 0);
            }
        }
        __syncthreads();
#pragma unroll
        for (int tile = 0; tile < 4; tile++) {
            int col = n0 + 16 * tile + l15;
            float bias = b2[col];
#pragma unroll
            for (int reg = 0; reg < 4; reg++) {
                int row = q * 4 + reg;
                Ht[m0 + row][col] = acc[tile][reg] + bias;
            }
        }
    }
    __syncthreads();

    for (int i = t; i < G_ROWS * 32; i += 256) {
        int r = i >> 5, c4 = i & 31;
        int row = base + r;
        if (row < N_NODES)
            *((float4*)(out + (size_t)row * NF + c4 * 4)) = *((const float4*)&Ht[r][c4 * 4]);
    }
}

// ======= round-6 3-dispatch path (fallback if cooperative launch unavailable) ====
__global__ __launch_bounds__(256, 6) void fused_gather_gemm1_bf16(
    const unsigned short* __restrict__ xb,
    const int* __restrict__ counts,
    const int* __restrict__ bucket,
    const int* __restrict__ ovfcnt,
    const int* __restrict__ ovf,
    const unsigned short* __restrict__ Wb,
    const float* __restrict__ b1,
    unsigned short* __restrict__ buf,
    float* __restrict__ P) {
    __shared__ __align__(16) char smem[G_ROWS * HP * 4];
    unsigned short (*At)[AP] = (unsigned short (*)[AP])smem;
    float (*Ht)[HP] = (float (*)[HP])smem;

    int t = threadIdx.x;
    int wave = t >> 6, lane = t & 63;
    int base = blockIdx.x * G_ROWS;
    int nrows = N_NODES - base; if (nrows > G_ROWS) nrows = G_ROWS;

    const unsigned int* x2 = (const unsigned int*)xb;
    int novf = *ovfcnt; if (novf > OVFCAP) novf = OVFCAP;

    for (int nn = 0; nn < 8; nn++) {
        int r = wave * 8 + nn;
        int node = base + r;
        unsigned int packed = 0u;
        if (node < N_NODES) {
            unsigned int u = x2[(size_t)node * 64 + lane];
            float ax = bflo(u), ay = bfhi(u);
            int deg = counts[node];
            int cnt = deg < CAP ? deg : CAP;
            const int* bkt = bucket + (size_t)node * CAP;
            int e = 0;
            for (; e + 15 < cnt; e += 16) {
                unsigned int uu[16];
#pragma unroll
                for (int k = 0; k < 16; k++) uu[k] = x2[(size_t)bkt[e + k] * 64 + lane];
#pragma unroll
                for (int k = 0; k < 16; k++) { ax += bflo(uu[k]); ay += bfhi(uu[k]); }
            }
            for (; e + 3 < cnt; e += 4) {
                unsigned int u0 = x2[(size_t)bkt[e] * 64 + lane];
                unsigned int u1 = x2[(size_t)bkt[e + 1] * 64 + lane];
                unsigned int u2 = x2[(size_t)bkt[e + 2] * 64 + lane];
                unsigned int u3 = x2[(size_t)bkt[e + 3] * 64 + lane];
                ax += bflo(u0) + bflo(u1) + bflo(u2) + bflo(u3);
                ay += bfhi(u0) + bfhi(u1) + bfhi(u2) + bfhi(u3);
            }
            for (; e < cnt; e++) {
                unsigned int u0 = x2[(size_t)bkt[e] * 64 + lane];
                ax += bflo(u0);
                ay += bfhi(u0);
            }
            if (deg > CAP) {
                for (int o = 0; o < novf; o++) {
                    if (ovf[2 * o] == node) {
                        unsigned int u0 = x2[(size_t)ovf[2 * o + 1] * 64 + lane];
                        ax += bflo(u0);
                        ay += bfhi(u0);
                    }
                }
            }
            packed = ((unsigned int)f2bf(ay) << 16) | (unsigned int)f2bf(ax);
        }
        ((unsigned int*)&At[r][0])[lane] = packed;
    }
    __syncthreads();

    int m0 = (wave & 1) * 16;
    int n0 = (wave >> 1) * 64;
    int l15 = lane & 15, q = lane >> 4;

    f32x4 acc[4];
#pragma unroll
    for (int i = 0; i < 4; i++) acc[i] = (f32x4){0.f, 0.f, 0.f, 0.f};
#pragma unroll
    for (int kc = 0; kc < 4; kc++) {
        short8 a = *((const short8*)&At[m0 + l15][kc * 32 + q * 8]);
#pragma unroll
        for (int tile = 0; tile < 4; tile++) {
            short8 b = *((const short8*)(Wb + (size_t)(n0 + 16 * tile + l15) * 128 + kc * 32 + q * 8));
            acc[tile] = __builtin_amdgcn_mfma_f32_16x16x32_bf16(a, b, acc[tile], 0, 0, 0);
        }
    }
    __syncthreads();
#pragma unroll
    for (int tile = 0; tile < 4; tile++) {
        int col = n0 + 16 * tile + l15;
        float bias = b1[col];
#pragma unroll
        for (int reg = 0; reg < 4; reg++) {
            int row = q * 4 + reg;
            Ht[m0 + row][col] = fmaxf(acc[tile][reg] + bias, 0.f);
        }
    }
    __syncthreads();

    for (int i = t; i < G_ROWS * 32; i += 256) {
        int r = i >> 5, c4 = i & 31;
        int row = base + r;
        if (row < N_NODES) {
            float4 v = *((const float4*)&Ht[r][c4 * 4]);
            ushort4 u;
            u.x = f2bf(v.x); u.y = f2bf(v.y); u.z = f2bf(v.z); u.w = f2bf(v.w);
            *((ushort4*)(buf + (size_t)row * NF + c4 * 4)) = u;
        }
    }

    {
        int f = t & 127;
        bool issq = (t >= 128);
        float s = 0.f;
        for (int r = 0; r < nrows; r++) {
            float v = Ht[r][f];
            s += issq ? v * v : v;
        }
        P[(size_t)t * NB + blockIdx.x] = s;
    }
}

__global__ __launch_bounds__(256) void bn_reduce(const float* __restrict__ P,
                                                 const float* __restrict__ gamma,
                                                 const float* __restrict__ beta,
                                                 float* __restrict__ ab) {
    __shared__ float s1[256], s2[256];
    int f = blockIdx.x;
    int j = threadIdx.x;
    float a = 0.f, b = 0.f;
    for (int k = j; k < GBLOCKS; k += 256) {
        a += P[(size_t)f * NB + k];
        b += P[(size_t)(128 + f) * NB + k];
    }
    s1[j] = a; s2[j] = b;
    __syncthreads();
    for (int off = 128; off > 0; off >>= 1) {
        if (j < off) { s1[j] += s1[j + off]; s2[j] += s2[j + off]; }
        __syncthreads();
    }
    if (j == 0) {
        float mean = s1[0] * (1.0f / N_NODES);
        float var = s2[0] * (1.0f / N_NODES) - mean * mean;
        float rstd = rsqrtf(var + BN_EPS);
        float aa = gamma[f] * rstd;
        float cc = beta[f] - mean * aa;
        ab[f] = aa;
        ab[128 + f] = cc;
    }
}

__global__ __launch_bounds__(256) void gemm2_bf16(
    const unsigned short* __restrict__ buf,
    const unsigned short* __restrict__ Wb,
    const float* __restrict__ b2,
    const float* __restrict__ ab,
    float* __restrict__ out) {
    __shared__ __align__(16) char smem[G_ROWS * HP * 4];
    unsigned short (*At)[AP] = (unsigned short (*)[AP])smem;
    float (*Ht)[HP] = (float (*)[HP])smem;

    int t = threadIdx.x;
    int base = blockIdx.x * G_ROWS;
    int nrows = N_NODES - base; if (nrows > G_ROWS) nrows = G_ROWS;

    for (int i = t; i < G_ROWS * 32; i += 256) {
        int r = i >> 5, c4 = i & 31;
        ushort4 u = make_ushort4(0, 0, 0, 0);
        if (r < nrows) {
            ushort4 hv = *((const ushort4*)(buf + (size_t)(base + r) * NF + c4 * 4));
            float4 av = ((const float4*)ab)[c4];
            float4 cv = ((const float4*)(ab + 128))[c4];
            u.x = f2bf(bf2f(hv.x) * av.x + cv.x);
            u.y = f2bf(bf2f(hv.y) * av.y + cv.y);
            u.z = f2bf(bf2f(hv.z) * av.z + cv.z);
            u.w = f2bf(bf2f(hv.w) * av.w + cv.w);
        }
        *((ushort4*)&At[r][c4 * 4]) = u;
    }
    __syncthreads();

    int wave = t >> 6, lane = t & 63;
    int m0 = (wave & 1) * 16;
    int n0 = (wave >> 1) * 64;
    int l15 = lane & 15, q = lane >> 4;

    f32x4 acc[4];
#pragma unroll
    for (int i = 0; i < 4; i++) acc[i] = (f32x4){0.f, 0.f, 0.f, 0.f};
#pragma unroll
    for (int kc = 0; kc < 4; kc++) {
        short8 a = *((const short8*)&At[m0 + l15][kc * 32 + q * 8]);
#pragma unroll
        for (int tile = 0; tile < 4; tile++) {
            short8 b = *((const short8*)(Wb + (size_t)(n0 + 16 * tile + l15) * 128 + kc * 32 + q * 8));
            acc[tile] = __builtin_amdgcn_mfma_f32_16x16x32_bf16(a, b, acc[tile], 0, 0, 0);
        }
    }
    __syncthreads();
#pragma unroll
    for (int tile = 0; tile < 4; tile++) {
        int col = n0 + 16 * tile + l15;
        float bias = b2[col];
#pragma unroll
        for (int reg = 0; reg < 4; reg++) {
            int row = q * 4 + reg;
            Ht[m0 + row][col] = acc[tile][reg] + bias;
        }
    }
    __syncthreads();

    for (int i = t; i < G_ROWS * 32; i += 256) {
        int r = i >> 5, c4 = i & 31;
        int row = base + r;
        if (row < N_NODES)
            *((float4*)(out + (size_t)row * NF + c4 * 4)) = *((const float4*)&Ht[r][c4 * 4]);
    }
}

// =============== fp32 fallback path (ws too small for bf16 tables) ===========
__global__ void finalize_bn(const float* __restrict__ stats,
                            const float* __restrict__ gamma,
                            const float* __restrict__ beta,
                            float* __restrict__ ab) {
    int f = threadIdx.x;
    if (f < 128) {
        float mean = stats[f] * (1.0f / N_NODES);
        float var = stats[128 + f] * (1.0f / N_NODES) - mean * mean;
        float rstd = rsqrtf(var + BN_EPS);
        float a = gamma[f] * rstd;
        float c = beta[f] - mean * a;
        ab[f] = a;
        ab[128 + f] = c;
    }
}

__global__ __launch_bounds__(256) void fused_gather_gemm1_f32(
    const float* __restrict__ xv,
    const int* __restrict__ counts,
    const int* __restrict__ bucket,
    const int* __restrict__ ovfcnt,
    const int* __restrict__ ovf,
    const unsigned short* __restrict__ Wb,
    const float* __restrict__ b1,
    float* __restrict__ hout,
    float* __restrict__ stats) {
    __shared__ unsigned short At[G_ROWS][AP];
    __shared__ float Ht[G_ROWS][HP];

    int t = threadIdx.x;
    int wave = t >> 6, lane = t & 63;
    int base = blockIdx.x * G_ROWS;
    int nrows = N_NODES - base; if (nrows > G_ROWS) nrows = G_ROWS;

    const float2* xf2 = (const float2*)xv;
    int novf = *ovfcnt; if (novf > OVFCAP) novf = OVFCAP;

    for (int nn = 0; nn < 8; nn++) {
        int r = wave * 8 + nn;
        int node = base + r;
        float2 acc = make_float2(0.f, 0.f);
        if (node < N_NODES) {
            acc = xf2[(size_t)node * 64 + lane];
            int deg = counts[node];
            int cnt = deg < CAP ? deg : CAP;
            const int* bkt = bucket + (size_t)node * CAP;
            for (int e = 0; e < cnt; e++) {
                float2 v0 = xf2[(size_t)bkt[e] * 64 + lane];
                acc.x += v0.x;
                acc.y += v0.y;
            }
            if (deg > CAP) {
                for (int o = 0; o < novf; o++) {
                    if (ovf[2 * o] == node) {
                        float2 v0 = xf2[(size_t)ovf[2 * o + 1] * 64 + lane];
                        acc.x += v0.x;
                        acc.y += v0.y;
                    }
                }
            }
        }
        unsigned int packed = ((unsigned int)f2bf(acc.y) << 16) | (unsigned int)f2bf(acc.x);
        *((unsigned int*)&At[r][lane * 2]) = packed;
    }
    __syncthreads();

    int m0 = (wave & 1) * 16;
    int n0 = (wave >> 1) * 64;
    int l15 = lane & 15, q = lane >> 4;

    f32x4 acc[4];
#pragma unroll
    for (int i = 0; i < 4; i++) acc[i] = (f32x4){0.f, 0.f, 0.f, 0.f};
#pragma unroll
    for (int kc = 0; kc < 4; kc++) {
        short8 a = *((const short8*)&At[m0 + l15][kc * 32 + q * 8]);
#pragma unroll
        for (int tile = 0; tile < 4; tile++) {
            short8 b = *((const short8*)(Wb + (size_t)(n0 + 16 * tile + l15) * 128 + kc * 32 + q * 8));
            acc[tile] = __builtin_amdgcn_mfma_f32_16x16x32_bf16(a, b, acc[tile], 0, 0, 0);
        }
    }
#pragma unroll
    for (int tile = 0; tile < 4; tile++) {
        int col = n0 + 16 * tile + l15;
        float bias = b1[col];
#pragma unroll
        for (int reg = 0; reg < 4; reg++) {
            int row = q * 4 + reg;
            Ht[m0 + row][col] = fmaxf(acc[tile][reg] + bias, 0.f);
        }
    }
    __syncthreads();

    for (int i = t; i < G_ROWS * 32; i += 256) {
        int r = i >> 5, c4 = i & 31;
        int row = base + r;
        if (row < N_NODES)
            *((float4*)(hout + (size_t)row * NF + c4 * 4)) = *((const float4*)&Ht[r][c4 * 4]);
    }

    if (t < 128) {
        float s = 0.f, sq = 0.f;
        for (int r = 0; r < nrows; r++) {
            float v = Ht[r][t];
            s += v; sq += v * v;
        }
        atomicAdd(&stats[t], s);
        atomicAdd(&stats[128 + t], sq);
    }
}

__global__ __launch_bounds__(256) void gemm2_f32(
    float* __restrict__ h,
    const unsigned short* __restrict__ Wb,
    const float* __restrict__ b2,
    const float* __restrict__ ab) {
    __shared__ unsigned short At[G_ROWS][AP];
    __shared__ float Ht[G_ROWS][HP];

    int t = threadIdx.x;
    int base = blockIdx.x * G_ROWS;
    int nrows = N_NODES - base; if (nrows > G_ROWS) nrows = G_ROWS;

    for (int i = t; i < G_ROWS * 32; i += 256) {
        int r = i >> 5, c4 = i & 31;
        float4 v = make_float4(0.f, 0.f, 0.f, 0.f);
        if (r < nrows) {
            float4 hv = ((const float4*)(h + (size_t)(base + r) * NF))[c4];
            float4 av = ((const float4*)ab)[c4];
            float4 cv = ((const float4*)(ab + 128))[c4];
            v.x = hv.x * av.x + cv.x;
            v.y = hv.y * av.y + cv.y;
            v.z = hv.z * av.z + cv.z;
            v.w = hv.w * av.w + cv.w;
        }
        ushort4 u;
        u.x = f2bf(v.x); u.y = f2bf(v.y); u.z = f2bf(v.z); u.w = f2bf(v.w);
        *((ushort4*)&At[r][c4 * 4]) = u;
    }
    __syncthreads();

    int wave = t >> 6, lane = t & 63;
    int m0 = (wave & 1) * 16;
    int n0 = (wave >> 1) * 64;
    int l15 = lane & 15, q = lane >> 4;

    f32x4 acc[4];
#pragma unroll
    for (int i = 0; i < 4; i++) acc[i] = (f32x4){0.f, 0.f, 0.f, 0.f};
#pragma unroll
    for (int kc = 0; kc < 4; kc++) {
        short8 a = *((const short8*)&At[m0 + l15][kc * 32 + q * 8]);
#pragma unroll
        for (int tile = 0; tile < 4; tile++) {
            short8 b = *((const short8*)(Wb + (size_t)(n0 + 16 * tile + l15) * 128 + kc * 32 + q * 8));
            acc[tile] = __builtin_amdgcn_mfma_f32_16x16x32_bf16(a, b, acc[tile], 0, 0, 0);
        }
    }
#pragma unroll
    for (int tile = 0; tile < 4; tile++) {
        int col = n0 + 16 * tile + l15;
        float bias = b2[col];
#pragma unroll
        for (int reg = 0; reg < 4; reg++) {
            int row = q * 4 + reg;
            Ht[m0 + row][col] = acc[tile][reg] + bias;
        }
    }
    __syncthreads();

    for (int i = t; i < G_ROWS * 32; i += 256) {
        int r = i >> 5, c4 = i & 31;
        int row = base + r;
        if (row < N_NODES)
            *((float4*)(h + (size_t)row * NF + c4 * 4)) = *((const float4*)&Ht[r][c4 * 4]);
    }
}

extern "C" void kernel_launch(void* const* d_in, const int* in_sizes, int n_in,
                              void* d_out, int out_size, void* d_ws, size_t ws_size,
                              hipStream_t stream) {
    const float* x     = (const float*)d_in[0];
    const int*   ei    = (const int*)d_in[1];
    const float* W1    = (const float*)d_in[2];
    const float* b1    = (const float*)d_in[3];
    const float* gamma = (const float*)d_in[4];
    const float* beta  = (const float*)d_in[5];
    const float* W2    = (const float*)d_in[6];
    const float* b2    = (const float*)d_in[7];

    float* out = (float*)d_out;

    // Workspace layout (~33.9 MB)
    float*          stats    = (float*)d_ws;                    // 256 f
    float*          ab       = stats + 256;                     // 256 f
    float*          P        = ab + 256;                        // 256*NB f (~1.6 MB)
    unsigned short* Wb1      = (unsigned short*)(P + 256 * NB); // 16384 us
    unsigned short* Wb2      = Wb1 + 128 * 128;                 // 16384 us
    int*            counts   = (int*)(Wb2 + 128 * 128);         // 50000 i
    int*            ovfcnt   = counts + N_NODES;                // 16 i ([0]=ovf, [2..3]=barrier)
    int*            ovf      = ovfcnt + 16;                     // 2*OVFCAP i (64 KB)
    int*            bucket   = ovf + 2 * OVFCAP;                // 50000*CAP i (6.4 MB)
    unsigned short* xb       = (unsigned short*)(bucket + (size_t)N_NODES * CAP); // 12.8 MB
    unsigned short* buf      = xb + (size_t)N_NODES * NF;       // 12.8 MB (fallback only)

    size_t need = (size_t)((char*)(buf + (size_t)N_NODES * NF) - (char*)d_ws);
    size_t need_fb = (size_t)((char*)xb - (char*)d_ws);
    bool bf16_path = ws_size >= need;

    if (bf16_path) {
        hipMemsetAsync(counts, 0, (N_NODES + 16) * sizeof(int), stream);  // counts+ovfcnt+barrier
        scatter_build<<<SC_BLK + CV_BLK, 256, 0, stream>>>(
            ei, counts, ovfcnt, ovf, bucket, x, xb, W1, W2, Wb1, Wb2, 1);

        // Mega path: cooperative launch guarantees co-residency for the grid
        // barrier (deadlock-proof: error -> fall back to 3-dispatch path).
        bool mega_ok = false;
        static int s_occ = -1;
        if (s_occ < 0) {
            int o = 0;
            if (hipOccupancyMaxActiveBlocksPerMultiprocessor(&o, mega_bf16, 256, 0) != hipSuccess)
                o = 0;
            s_occ = o;
        }
        if (s_occ * 256 >= GBLOCKS) {
            const unsigned short* a_xb = xb;   const int* a_counts = counts;
            const int* a_bucket = bucket;      const int* a_ovfcnt = ovfcnt;
            const int* a_ovf = ovf;            const unsigned short* a_Wb1 = Wb1;
            const float* a_b1 = b1;            const unsigned short* a_Wb2 = Wb2;
            const float* a_b2 = b2;            const float* a_gamma = gamma;
            const float* a_beta = beta;        float* a_P = P;
            float* a_ab = ab;                  int* a_bar = ovfcnt + 2;
            float* a_out = out;
            void* args[] = {
                (void*)&a_xb, (void*)&a_counts, (void*)&a_bucket, (void*)&a_ovfcnt,
                (void*)&a_ovf, (void*)&a_Wb1, (void*)&a_b1, (void*)&a_Wb2,
                (void*)&a_b2, (void*)&a_gamma, (void*)&a_beta, (void*)&a_P,
                (void*)&a_ab, (void*)&a_bar, (void*)&a_out };
            hipError_t err = hipLaunchCooperativeKernel(
                (const void*)mega_bf16, dim3(GBLOCKS), dim3(256), args, 0, stream);
            mega_ok = (err == hipSuccess);
        }
        if (!mega_ok) {
            fused_gather_gemm1_bf16<<<GBLOCKS, 256, 0, stream>>>(
                xb, counts, bucket, ovfcnt, ovf, Wb1, b1, buf, P);
            bn_reduce<<<128, 256, 0, stream>>>(P, gamma, beta, ab);
            gemm2_bf16<<<GBLOCKS, 256, 0, stream>>>(buf, Wb2, b2, ab, out);
        }
    } else if (ws_size >= need_fb) {
        hipMemsetAsync(counts, 0, (N_NODES + 16) * sizeof(int), stream);
        hipMemsetAsync(stats, 0, 256 * sizeof(float), stream);
        scatter_build<<<SC_BLK + CV_BLK, 256, 0, stream>>>(
            ei, counts, ovfcnt, ovf, bucket, x, (unsigned short*)0, W1, W2, Wb1, Wb2, 0);
        fused_gather_gemm1_f32<<<GBLOCKS, 256, 0, stream>>>(
            x, counts, bucket, ovfcnt, ovf, Wb1, b1, out, stats);
        finalize_bn<<<1, 128, 0, stream>>>(stats, gamma, beta, ab);
        gemm2_f32<<<GBLOCKS, 256, 0, stream>>>(out, Wb2, b2, ab);
    }
}